// Round 1
// baseline (74.360 us; speedup 1.0000x reference)
//
#include <hip/hip_runtime.h>
#include <hip/hip_bf16.h>

// Poincare pairwise distance:
//   d(x,p) = acosh(1 + 2*||x-p||^2 / ((1-||x||^2)(1-||p||^2)))   (c = 1)
// B=16384, N=4096, D=64.  Output 16384x4096 f32 (256 MiB) -> write-bound.
// GEMM part (x @ p^T) done with bf16 MFMA 16x16x32; x^2/p^2 from f32 exactly.

constexpr int BATCH = 16384;
constexpr int NCON  = 4096;
constexpr int DIM   = 64;
constexpr int TM    = 128;
constexpr int TN    = 128;
constexpr int NT_N  = NCON / TN;   // 32 tiles along N
constexpr float EPS = 1e-7f;

typedef float  f32x4  __attribute__((ext_vector_type(4)));
typedef __bf16 bf16x8 __attribute__((ext_vector_type(8)));

__global__ __launch_bounds__(256, 2)
void poincare_pairwise_kernel(const float* __restrict__ emb,
                              const float* __restrict__ proto,
                              float* __restrict__ out)
{
    // LDS: bf16 tiles, XOR-swizzled along k to kill the stride-128B bank
    // conflict on ds_read_b128 (element-index swizzle: k ^= (row&7)<<3).
    __shared__ __bf16 As[TM * DIM];   // 16 KiB
    __shared__ __bf16 Bs[TN * DIM];   // 16 KiB
    __shared__ float  x2s[TM];
    __shared__ float  p2s[TN];

    const int tid = threadIdx.x;
    const int bid = blockIdx.x;
    const int mt  = bid >> 5;          // 128 tiles along M
    const int nt  = bid & (NT_N - 1);  // 32 tiles along N
    const int m0  = mt * TM;
    const int n0  = nt * TN;

    // ---------- stage A tile (128 rows x 64) ----------
    // flat float4 index: row = flat>>4, kq = flat&15. Coalesced 16B/lane.
    #pragma unroll
    for (int p = 0; p < 8; ++p) {
        int flat = p * 256 + tid;
        int row  = flat >> 4;
        int kq   = flat & 15;
        f32x4 v = *reinterpret_cast<const f32x4*>(emb + (size_t)(m0 + row) * DIM + kq * 4);
        float ss = v.x * v.x + v.y * v.y + v.z * v.z + v.w * v.w;
        ss += __shfl_xor(ss, 1);
        ss += __shfl_xor(ss, 2);
        ss += __shfl_xor(ss, 4);
        ss += __shfl_xor(ss, 8);
        if (kq == 0) x2s[row] = ss;
        __bf16 b4[4] = {(__bf16)v.x, (__bf16)v.y, (__bf16)v.z, (__bf16)v.w};
        int ke = (kq * 4) ^ ((row & 7) << 3);
        *reinterpret_cast<uint2*>(&As[row * DIM + ke]) = *reinterpret_cast<const uint2*>(b4);
    }
    // ---------- stage B tile (128 rows x 64) ----------
    #pragma unroll
    for (int p = 0; p < 8; ++p) {
        int flat = p * 256 + tid;
        int row  = flat >> 4;
        int kq   = flat & 15;
        f32x4 v = *reinterpret_cast<const f32x4*>(proto + (size_t)(n0 + row) * DIM + kq * 4);
        float ss = v.x * v.x + v.y * v.y + v.z * v.z + v.w * v.w;
        ss += __shfl_xor(ss, 1);
        ss += __shfl_xor(ss, 2);
        ss += __shfl_xor(ss, 4);
        ss += __shfl_xor(ss, 8);
        if (kq == 0) p2s[row] = ss;
        __bf16 b4[4] = {(__bf16)v.x, (__bf16)v.y, (__bf16)v.z, (__bf16)v.w};
        int ke = (kq * 4) ^ ((row & 7) << 3);
        *reinterpret_cast<uint2*>(&Bs[row * DIM + ke]) = *reinterpret_cast<const uint2*>(b4);
    }
    __syncthreads();

    // ---------- MFMA: each wave owns a 64x64 sub-tile ----------
    const int lane = tid & 63;
    const int wid  = tid >> 6;
    const int wr   = wid >> 1;         // 2 waves along M
    const int wc   = wid & 1;          // 2 waves along N
    const int lr   = lane & 15;        // row/col within 16-fragment
    const int lk   = (lane >> 4) * 8;  // k offset within 32

    bf16x8 af[4][2], bfr[4][2];
    #pragma unroll
    for (int m = 0; m < 4; ++m) {
        int row = wr * 64 + m * 16 + lr;
        #pragma unroll
        for (int kk = 0; kk < 2; ++kk) {
            int ke = (kk * 32 + lk) ^ ((row & 7) << 3);
            af[m][kk] = *reinterpret_cast<const bf16x8*>(&As[row * DIM + ke]);
        }
    }
    #pragma unroll
    for (int n = 0; n < 4; ++n) {
        int row = wc * 64 + n * 16 + lr;
        #pragma unroll
        for (int kk = 0; kk < 2; ++kk) {
            int ke = (kk * 32 + lk) ^ ((row & 7) << 3);
            bfr[n][kk] = *reinterpret_cast<const bf16x8*>(&Bs[row * DIM + ke]);
        }
    }

    f32x4 acc[4][4] = {};
    #pragma unroll
    for (int kk = 0; kk < 2; ++kk)
        #pragma unroll
        for (int m = 0; m < 4; ++m)
            #pragma unroll
            for (int n = 0; n < 4; ++n)
                acc[m][n] = __builtin_amdgcn_mfma_f32_16x16x32_bf16(
                    af[m][kk], bfr[n][kk], acc[m][n], 0, 0, 0);

    // ---------- epilogue: hyperbolic distance + store ----------
    // C/D layout (m89-verified): col = lane&15, row = (lane>>4)*4 + j.
    const int rq = (lane >> 4) * 4;
    #pragma unroll
    for (int m = 0; m < 4; ++m) {
        int rloc0 = wr * 64 + m * 16 + rq;
        #pragma unroll
        for (int n = 0; n < 4; ++n) {
            int cloc = wc * 64 + n * 16 + lr;
            float p2 = p2s[cloc];
            size_t cg = (size_t)(n0 + cloc);
            #pragma unroll
            for (int j = 0; j < 4; ++j) {
                int   rloc = rloc0 + j;
                float x2   = x2s[rloc];
                float xp   = acc[m][n][j];
                float sq   = fmaxf(x2 + p2 - 2.0f * xp, 0.0f);
                float den  = fmaxf((1.0f - x2) * (1.0f - p2), EPS);
                float t    = 2.0f * sq * __builtin_amdgcn_rcpf(den);
                t = fmaxf(t, EPS);  // matches arg = max(arg, 1+EPS)
                float s = __builtin_amdgcn_sqrtf(t * (t + 2.0f));
                float d = 0.693147180559945f * __builtin_amdgcn_logf(1.0f + t + s);
                out[(size_t)(m0 + rloc) * NCON + cg] = d;
            }
        }
    }
}

extern "C" void kernel_launch(void* const* d_in, const int* in_sizes, int n_in,
                              void* d_out, int out_size, void* d_ws, size_t ws_size,
                              hipStream_t stream) {
    const float* emb   = (const float*)d_in[0];
    const float* proto = (const float*)d_in[1];
    float* out = (float*)d_out;

    dim3 grid((BATCH / TM) * (NCON / TN));  // 128 * 32 = 4096
    dim3 block(256);
    poincare_pairwise_kernel<<<grid, block, 0, stream>>>(emb, proto, out);
}